// Round 13
// baseline (123.976 us; speedup 1.0000x reference)
//
#include <hip/hip_runtime.h>

// B=4, Sx=Sy=512, H=128, D=2H=256, fp32.
// e1 = exp2(2log2e * x@W1^T)  (stored PRE-SWIZZLED: [b][c][hq][s^hq] float4)
// e2 = exp2(2log2e * y@W2^T)  (linear)
// tanh(s1+s2) = 1 - 2/(e1*e2+1); score = sum_h vc[h]*tanh(.)
// constant sum_h vc[h] dropped (softmax shift-invariant). P = softmax_s;
// out = P @ x. Quad-rcp: one v_rcp per 4 h.
//
// R5-R7: allocator can pin wide kernels at 32 VGPRs and spill prefetch regs
// (200 MB scratch). Fix: global_load_lds DMA staging (zero staging VGPRs).
// R8: harness 256 MiB 0xAA ws-fill = ~41 us of every iteration (immovable).
// R12: fused-epilogue experiment exposed score at 48 us, VALUBusy 44% —
// five (t, h-slice) decompositions all ~50 us: the cross-wave partial
// reduction + tid<256 phases are the overhead, not the math (~7 us VALU).
// R13: wave = ONE t x ALL h. No cross-wave reduce, no partial LDS, softmax
// in-wave from v[8] registers. e2/vc via LDS broadcast table (8 KB).
// LDS 72 KB -> 2 blocks/CU. pax = proven R9 shape; proj = fused R11.

#define NB 4
#define SEQ 512
#define HDIM 128
#define DDIM 256

static constexpr float TWO_LOG2E = 2.8853900817779268f; // 2*log2(e)
static constexpr float LOG2E     = 1.4426950408889634f;

__device__ __forceinline__ void gload_lds16(const void* g, void* l) {
    __builtin_amdgcn_global_load_lds(
        (const __attribute__((address_space(1))) void*)g,
        (__attribute__((address_space(3))) void*)l, 16, 0, 0);
}

// ---------------- Kernel A: projections + exp2 (unchanged R11/R12) ---------
__global__ __launch_bounds__(256) void proj_kernel(
    const float* __restrict__ x, const float* __restrict__ y,
    const float* __restrict__ W1, const float* __restrict__ W2,
    float* __restrict__ e1sw, float* __restrict__ e2)
{
    __shared__ float As[2048];      // [8 r][256 k]
    __shared__ float sPr[8192];     // [8 ks][8 r][128 h]
    const int tid = threadIdx.x;
    const int blk = blockIdx.x;           // [0,512)
    const int gr0 = blk * 8;              // global virtual row base [0,4096)

    const float* in; const float* W; int srow;
    if (gr0 < 2048) { in = x; W = W1; srow = gr0; }
    else            { in = y; W = W2; srow = gr0 - 2048; }

    {
        const int r = tid >> 5, kk = tid & 31;
        *(float4*)&As[r * 256 + kk * 8] =
            *(const float4*)&in[(srow + r) * 256 + kk * 8];
        *(float4*)&As[r * 256 + kk * 8 + 4] =
            *(const float4*)&in[(srow + r) * 256 + kk * 8 + 4];
    }
    __syncthreads();

    const int hq = tid & 31;
    const int ks = tid >> 5;

    float4 acc4[8];
    #pragma unroll
    for (int r = 0; r < 8; ++r) acc4[r] = make_float4(0.f, 0.f, 0.f, 0.f);

    #pragma unroll
    for (int u = 0; u < 8; ++u) {
        const int kof = ks * 32 + u * 4;
        const float4 w0 = *(const float4*)&W[(4*hq + 0) * 256 + kof];
        const float4 w1 = *(const float4*)&W[(4*hq + 1) * 256 + kof];
        const float4 w2 = *(const float4*)&W[(4*hq + 2) * 256 + kof];
        const float4 w3 = *(const float4*)&W[(4*hq + 3) * 256 + kof];
        #pragma unroll
        for (int r = 0; r < 8; ++r) {
            const float4 a = *(const float4*)&As[r * 256 + kof];
            acc4[r].x = fmaf(a.w,w0.w, fmaf(a.z,w0.z, fmaf(a.y,w0.y, fmaf(a.x,w0.x, acc4[r].x))));
            acc4[r].y = fmaf(a.w,w1.w, fmaf(a.z,w1.z, fmaf(a.y,w1.y, fmaf(a.x,w1.x, acc4[r].y))));
            acc4[r].z = fmaf(a.w,w2.w, fmaf(a.z,w2.z, fmaf(a.y,w2.y, fmaf(a.x,w2.x, acc4[r].z))));
            acc4[r].w = fmaf(a.w,w3.w, fmaf(a.z,w3.z, fmaf(a.y,w3.y, fmaf(a.x,w3.x, acc4[r].w))));
        }
    }
    #pragma unroll
    for (int r = 0; r < 8; ++r)
        *(float4*)&sPr[ks * 1024 + r * 128 + hq * 4] = acc4[r];
    __syncthreads();
    {
        const int r = tid >> 5, h4 = tid & 31;
        float4 s = make_float4(0.f, 0.f, 0.f, 0.f);
        #pragma unroll
        for (int k2 = 0; k2 < 8; ++k2) {
            const float4 p = *(const float4*)&sPr[k2 * 1024 + r * 128 + h4 * 4];
            s.x += p.x; s.y += p.y; s.z += p.z; s.w += p.w;
        }
        float4 o;
        o.x = __builtin_amdgcn_exp2f(s.x * TWO_LOG2E);
        o.y = __builtin_amdgcn_exp2f(s.y * TWO_LOG2E);
        o.z = __builtin_amdgcn_exp2f(s.z * TWO_LOG2E);
        o.w = __builtin_amdgcn_exp2f(s.w * TWO_LOG2E);
        const int gr = gr0 + r;
        if (gr < 2048) {
            const int b = gr >> 9, sx = gr & 511;
            const int c = sx >> 6, sl = sx & 63;
            ((float4*)e1sw)[((b * 8 + c) * 32 + h4) * 64 + (sl ^ h4)] = o;
        } else {
            ((float4*)e2)[(gr - 2048) * 32 + h4] = o;
        }
    }
}

// ---------------- Kernel B: scores + softmax -> P (v2: wave = 1 t x all h) -
// 256 blocks x 512 thr (8 waves). Block = (b, 8 t); wave w -> t = t0+w.
// Per chunk (64 s): each wave accumulates its t's score over all 32 h-quads:
// 1 per-lane b128 (e1, swizzled conflict-free) + 2 broadcast b128 (vc,e2
// from sVE table) + 14 VALU per quad. Per-chunk result -> v[c] registers.
// NO cross-wave reduction, NO partial-score LDS, softmax entirely in-wave.
// e1 via double-buffered global_load_lds DMA (4 x 1KB segs/wave/chunk).
__global__ __launch_bounds__(512) void score_kernel(
    const float* __restrict__ e1sw, const float* __restrict__ e2g,
    const float* __restrict__ vc,  float* __restrict__ P)
{
    __shared__ float4 sE1[2][2048];   // 2 x 32 KB
    __shared__ float  sVE[8 * 32 * 8]; // 8 KB: [t][quad][(vc4,e24)]

    const int tid  = threadIdx.x;
    const int b    = blockIdx.x >> 6;
    const int t0   = (blockIdx.x & 63) * 8;
    const int w    = tid >> 6;
    const int lane = tid & 63;
    const int wu   = __builtin_amdgcn_readfirstlane(w);

    // stage the vc/e2 table: [t][q][0..3]=vc quad, [4..7]=e2[t] quad
    if (tid < 256) {
        const int t = tid >> 5, q = tid & 31;
        *(float4*)&sVE[(t * 32 + q) * 8] = *(const float4*)&vc[q * 4];
    } else {
        const int i = tid - 256, t = i >> 5, q = i & 31;
        *(float4*)&sVE[(t * 32 + q) * 8 + 4] =
            *(const float4*)&e2g[(b * SEQ + t0 + t) * HDIM + q * 4];
    }

    const float4* e1c = (const float4*)e1sw + b * 16384;  // 8 chunks x 2048

    // issue chunk 0 DMA into buf 0 (4 x 1KB segments per wave)
    #pragma unroll
    for (int j = 0; j < 4; ++j) {
        const int seg = wu * 256 + j * 64;
        gload_lds16(e1c + seg + lane, &sE1[0][seg]);
    }

    const float* ve = &sVE[wu * 256];   // this wave's t row of the table
    float v[8];

    for (int c = 0; c < 8; ++c) {
        __syncthreads();   // drains DMA (buf[c&1] ready); sVE visible at c=0
        if (c < 7) {
            const float4* gch = e1c + (c + 1) * 2048;
            #pragma unroll
            for (int j = 0; j < 4; ++j) {
                const int seg = wu * 256 + j * 64;
                gload_lds16(gch + seg + lane, &sE1[(c + 1) & 1][seg]);
            }
        }
        float acc = 0.f;
        const float4* buf = sE1[c & 1];
        #pragma unroll 8
        for (int q = 0; q < 32; ++q) {
            const float4 e1 = buf[q * 64 + (lane ^ q)];
            const float4 vv = *(const float4*)&ve[q * 8];
            const float4 ee = *(const float4*)&ve[q * 8 + 4];
            const float f1 = fmaf(e1.x, ee.x, 1.f);
            const float f2 = fmaf(e1.y, ee.y, 1.f);
            const float f3 = fmaf(e1.z, ee.z, 1.f);
            const float f4 = fmaf(e1.w, ee.w, 1.f);
            const float f12 = f1 * f2, f34 = f3 * f4;
            const float n12 = fmaf(vv.x, f2, vv.y * f1);
            const float n34 = fmaf(vv.z, f4, vv.w * f3);
            const float num = fmaf(n12, f34, n34 * f12);
            acc = fmaf(num, __builtin_amdgcn_rcpf(f12 * f34), acc);
        }
        v[c] = -2.f * acc;   // score for s = c*64 + lane
    }

    // in-wave softmax over this wave's 512 scores
    float m = -1e30f;
    #pragma unroll
    for (int j = 0; j < 8; ++j) m = fmaxf(m, v[j]);
    #pragma unroll
    for (int off = 32; off; off >>= 1) m = fmaxf(m, __shfl_xor(m, off));
    float sum = 0.f;
    #pragma unroll
    for (int j = 0; j < 8; ++j) {
        v[j] = __builtin_amdgcn_exp2f((v[j] - m) * LOG2E);
        sum += v[j];
    }
    #pragma unroll
    for (int off = 32; off; off >>= 1) sum += __shfl_xor(sum, off);
    const float inv = __builtin_amdgcn_rcpf(sum);
    float* Prow = &P[(b * SEQ + t0 + w) * SEQ];
    #pragma unroll
    for (int j = 0; j < 8; ++j)
        Prow[j * 64 + lane] = v[j] * inv;
}

// ---------------- Kernel C: out = P @ x (proven R9 shape) ------------------
// 256 blocks x 256 thr. Block = (b, 8-t tile). Wave = s-quarter (128 s);
// lane = d-quad over all 256 d. Per s: 1 global b128 (x, L2-hot) +
// 2 broadcast b128 (8 probs) -> 32 FMAs. Cross-wave reduce in LDS.
__global__ __launch_bounds__(256) void pax_kernel(
    const float* __restrict__ P, const float* __restrict__ x,
    float* __restrict__ out)
{
    __shared__ float sP[SEQ * 8];        // 16 KB: [s][t]
    __shared__ float sRed[4 * 8 * DDIM]; // 32 KB: [w][t][d]
    const int tid = threadIdx.x;
    const int b   = blockIdx.x >> 6;
    const int t0  = (blockIdx.x & 63) * 8;
    const int w    = tid >> 6;
    const int lane = tid & 63;

    #pragma unroll
    for (int j = 0; j < 4; ++j) {
        const int i = tid + j * 256;          // [0,1024): t = i>>7, c4 = i&127
        const int t = i >> 7, c4 = i & 127;
        const float4 p = *(const float4*)&P[(b * SEQ + t0 + t) * SEQ + c4 * 4];
        sP[(c4 * 4 + 0) * 8 + t] = p.x;
        sP[(c4 * 4 + 1) * 8 + t] = p.y;
        sP[(c4 * 4 + 2) * 8 + t] = p.z;
        sP[(c4 * 4 + 3) * 8 + t] = p.w;
    }
    __syncthreads();

    const float4* x4 = (const float4*)x;
    float4 acc[8];
    #pragma unroll
    for (int t = 0; t < 8; ++t) acc[t] = make_float4(0.f, 0.f, 0.f, 0.f);

    #pragma unroll 4
    for (int si = 0; si < 128; ++si) {
        const int s = w * 128 + si;
        const float4 xv  = x4[(b * SEQ + s) * 64 + lane];
        const float4 p03 = *(const float4*)&sP[s * 8];
        const float4 p47 = *(const float4*)&sP[s * 8 + 4];
        acc[0].x = fmaf(p03.x, xv.x, acc[0].x); acc[0].y = fmaf(p03.x, xv.y, acc[0].y);
        acc[0].z = fmaf(p03.x, xv.z, acc[0].z); acc[0].w = fmaf(p03.x, xv.w, acc[0].w);
        acc[1].x = fmaf(p03.y, xv.x, acc[1].x); acc[1].y = fmaf(p03.y, xv.y, acc[1].y);
        acc[1].z = fmaf(p03.y, xv.z, acc[1].z); acc[1].w = fmaf(p03.y, xv.w, acc[1].w);
        acc[2].x = fmaf(p03.z, xv.x, acc[2].x); acc[2].y = fmaf(p03.z, xv.y, acc[2].y);
        acc[2].z = fmaf(p03.z, xv.z, acc[2].z); acc[2].w = fmaf(p03.z, xv.w, acc[2].w);
        acc[3].x = fmaf(p03.w, xv.x, acc[3].x); acc[3].y = fmaf(p03.w, xv.y, acc[3].y);
        acc[3].z = fmaf(p03.w, xv.z, acc[3].z); acc[3].w = fmaf(p03.w, xv.w, acc[3].w);
        acc[4].x = fmaf(p47.x, xv.x, acc[4].x); acc[4].y = fmaf(p47.x, xv.y, acc[4].y);
        acc[4].z = fmaf(p47.x, xv.z, acc[4].z); acc[4].w = fmaf(p47.x, xv.w, acc[4].w);
        acc[5].x = fmaf(p47.y, xv.x, acc[5].x); acc[5].y = fmaf(p47.y, xv.y, acc[5].y);
        acc[5].z = fmaf(p47.y, xv.z, acc[5].z); acc[5].w = fmaf(p47.y, xv.w, acc[5].w);
        acc[6].x = fmaf(p47.z, xv.x, acc[6].x); acc[6].y = fmaf(p47.z, xv.y, acc[6].y);
        acc[6].z = fmaf(p47.z, xv.z, acc[6].z); acc[6].w = fmaf(p47.z, xv.w, acc[6].w);
        acc[7].x = fmaf(p47.w, xv.x, acc[7].x); acc[7].y = fmaf(p47.w, xv.y, acc[7].y);
        acc[7].z = fmaf(p47.w, xv.z, acc[7].z); acc[7].w = fmaf(p47.w, xv.w, acc[7].w);
    }
    __syncthreads();
    float4* sRed4 = (float4*)sRed;     // [4 w][8 t][64 lanes]
    #pragma unroll
    for (int t = 0; t < 8; ++t)
        sRed4[w * 512 + t * 64 + lane] = acc[t];
    __syncthreads();
    #pragma unroll
    for (int j = 0; j < 8; ++j) {
        const int i = tid + j * 256;   // [0,2048): t = i>>8, d = i&255
        const int t = i >> 8, d = i & 255;
        const float r = sRed[0*2048 + t*256 + d] + sRed[1*2048 + t*256 + d]
                      + sRed[2*2048 + t*256 + d] + sRed[3*2048 + t*256 + d];
        out[(b * SEQ + t0 + t) * DDIM + d] = r;
    }
}

extern "C" void kernel_launch(void* const* d_in, const int* in_sizes, int n_in,
                              void* d_out, int out_size, void* d_ws, size_t ws_size,
                              hipStream_t stream) {
    const float* x   = (const float*)d_in[0];   // (4,512,256)
    const float* y   = (const float*)d_in[1];   // (4,512,256)
    const float* W1  = (const float*)d_in[2];   // (128,256)
    const float* W2  = (const float*)d_in[3];   // (128,256)
    const float* vc  = (const float*)d_in[4];   // (1,128)
    float* outp = (float*)d_out;                // (4,512,256)

    float* ws = (float*)d_ws;
    float* e1 = ws;                             // 1 MB (swizzled)
    float* e2 = ws + NB * SEQ * HDIM;           // 1 MB
    float* P  = ws + 2 * NB * SEQ * HDIM;       // 4 MB

    hipLaunchKernelGGL(proj_kernel,  dim3(512), dim3(256), 0, stream,
                       x, y, W1, W2, e1, e2);
    hipLaunchKernelGGL(score_kernel, dim3(256), dim3(512), 0, stream,
                       e1, e2, vc, P);
    hipLaunchKernelGGL(pax_kernel,   dim3(256), dim3(256), 0, stream,
                       P, x, outp);
}

// Round 14
// 119.114 us; speedup vs baseline: 1.0408x; 1.0408x over previous
//
#include <hip/hip_runtime.h>

// B=4, Sx=Sy=512, H=128, D=2H=256, fp32.
// e1 = exp2(2log2e * x@W1^T)  (stored PRE-SWIZZLED: [b][c][hq][s^hq] float4)
// e2 = exp2(2log2e * y@W2^T)  (linear)
// tanh(s1+s2) = 1 - 2/(e1*e2+1); score = sum_h vc[h]*tanh(.)
// constant sum_h vc[h] dropped (softmax shift-invariant). P = softmax_s;
// out = P @ x. Quad-rcp: one v_rcp per 4 h.
//
// Journal: R5-R7 allocator spill -> global_load_lds DMA staging. R8: 41 us
// harness ws-fill floor. R12: (t,h-slice)+cross-wave-reduce structures all
// ~50 us — reduce machinery is the overhead. R13: wave=1t×all-h shape, but
// sVE LDS broadcast table tripled LDS instrs (3 b128/quad) — regressed.
// R14: same shape, operands via SGPR *streaming*: h processed in 4 octants,
// 64 floats of vc/e2 s_loaded per octant (unroll 1 caps live range); inner
// loop = 1 LDS b128/quad. 512 blk x 4 waves, 64 KB dbuf, 2 blocks/CU.

#define NB 4
#define SEQ 512
#define HDIM 128
#define DDIM 256

static constexpr float TWO_LOG2E = 2.8853900817779268f; // 2*log2(e)
static constexpr float LOG2E     = 1.4426950408889634f;

__device__ __forceinline__ void gload_lds16(const void* g, void* l) {
    __builtin_amdgcn_global_load_lds(
        (const __attribute__((address_space(1))) void*)g,
        (__attribute__((address_space(3))) void*)l, 16, 0, 0);
}

// ---------------- Kernel A: projections + exp2 (unchanged R11) -------------
__global__ __launch_bounds__(256) void proj_kernel(
    const float* __restrict__ x, const float* __restrict__ y,
    const float* __restrict__ W1, const float* __restrict__ W2,
    float* __restrict__ e1sw, float* __restrict__ e2)
{
    __shared__ float As[2048];      // [8 r][256 k]
    __shared__ float sPr[8192];     // [8 ks][8 r][128 h]
    const int tid = threadIdx.x;
    const int blk = blockIdx.x;           // [0,512)
    const int gr0 = blk * 8;              // global virtual row base [0,4096)

    const float* in; const float* W; int srow;
    if (gr0 < 2048) { in = x; W = W1; srow = gr0; }
    else            { in = y; W = W2; srow = gr0 - 2048; }

    {
        const int r = tid >> 5, kk = tid & 31;
        *(float4*)&As[r * 256 + kk * 8] =
            *(const float4*)&in[(srow + r) * 256 + kk * 8];
        *(float4*)&As[r * 256 + kk * 8 + 4] =
            *(const float4*)&in[(srow + r) * 256 + kk * 8 + 4];
    }
    __syncthreads();

    const int hq = tid & 31;
    const int ks = tid >> 5;

    float4 acc4[8];
    #pragma unroll
    for (int r = 0; r < 8; ++r) acc4[r] = make_float4(0.f, 0.f, 0.f, 0.f);

    #pragma unroll
    for (int u = 0; u < 8; ++u) {
        const int kof = ks * 32 + u * 4;
        const float4 w0 = *(const float4*)&W[(4*hq + 0) * 256 + kof];
        const float4 w1 = *(const float4*)&W[(4*hq + 1) * 256 + kof];
        const float4 w2 = *(const float4*)&W[(4*hq + 2) * 256 + kof];
        const float4 w3 = *(const float4*)&W[(4*hq + 3) * 256 + kof];
        #pragma unroll
        for (int r = 0; r < 8; ++r) {
            const float4 a = *(const float4*)&As[r * 256 + kof];
            acc4[r].x = fmaf(a.w,w0.w, fmaf(a.z,w0.z, fmaf(a.y,w0.y, fmaf(a.x,w0.x, acc4[r].x))));
            acc4[r].y = fmaf(a.w,w1.w, fmaf(a.z,w1.z, fmaf(a.y,w1.y, fmaf(a.x,w1.x, acc4[r].y))));
            acc4[r].z = fmaf(a.w,w2.w, fmaf(a.z,w2.z, fmaf(a.y,w2.y, fmaf(a.x,w2.x, acc4[r].z))));
            acc4[r].w = fmaf(a.w,w3.w, fmaf(a.z,w3.z, fmaf(a.y,w3.y, fmaf(a.x,w3.x, acc4[r].w))));
        }
    }
    #pragma unroll
    for (int r = 0; r < 8; ++r)
        *(float4*)&sPr[ks * 1024 + r * 128 + hq * 4] = acc4[r];
    __syncthreads();
    {
        const int r = tid >> 5, h4 = tid & 31;
        float4 s = make_float4(0.f, 0.f, 0.f, 0.f);
        #pragma unroll
        for (int k2 = 0; k2 < 8; ++k2) {
            const float4 p = *(const float4*)&sPr[k2 * 1024 + r * 128 + h4 * 4];
            s.x += p.x; s.y += p.y; s.z += p.z; s.w += p.w;
        }
        float4 o;
        o.x = __builtin_amdgcn_exp2f(s.x * TWO_LOG2E);
        o.y = __builtin_amdgcn_exp2f(s.y * TWO_LOG2E);
        o.z = __builtin_amdgcn_exp2f(s.z * TWO_LOG2E);
        o.w = __builtin_amdgcn_exp2f(s.w * TWO_LOG2E);
        const int gr = gr0 + r;
        if (gr < 2048) {
            const int b = gr >> 9, sx = gr & 511;
            const int c = sx >> 6, sl = sx & 63;
            ((float4*)e1sw)[((b * 8 + c) * 32 + h4) * 64 + (sl ^ h4)] = o;
        } else {
            ((float4*)e2)[(gr - 2048) * 32 + h4] = o;
        }
    }
}

// ---------------- Kernel B: scores + softmax -> P (v3) ---------------------
// 512 blocks x 256 thr (4 waves). Block = (b, 4 t); wave w -> t = t0+w,
// ALL 128 h. No cross-wave reduce, no partial LDS, softmax in-wave.
// vc/e2 streamed through SGPRs one h-octant at a time (64 floats live;
// unroll 1 on the octant loop caps the live range). Inner loop: 1 per-lane
// LDS b128 (e1, swizzle conflict-free) + ~16 VALU per quad; scalar loads
// ride the SMEM pipe in parallel. e1 via double-buffered global_load_lds.
// LDS 64 KB -> 2 blocks/CU (two independent barrier groups overlap).
__global__ __launch_bounds__(256) void score_kernel(
    const float* __restrict__ e1sw, const float* __restrict__ e2g,
    const float* __restrict__ vc,  float* __restrict__ P)
{
    __shared__ float4 sE1[2][2048];   // 2 x 32 KB

    const int tid  = threadIdx.x;
    const int b    = blockIdx.x >> 7;
    const int t0   = (blockIdx.x & 127) * 4;
    const int w    = tid >> 6;
    const int lane = tid & 63;
    const int wu   = __builtin_amdgcn_readfirstlane(w);

    const float* e2row = &e2g[(b * SEQ + t0 + wu) * HDIM];
    const float4* e1c  = (const float4*)e1sw + b * 16384;  // 8 chunks x 2048

    // chunk 0 DMA into buf 0: wave stages 512 float4 = 8 x 64-lane segments
    #pragma unroll
    for (int j = 0; j < 8; ++j) {
        const int seg = wu * 512 + j * 64;
        gload_lds16(e1c + seg + lane, &sE1[0][seg]);
    }

    float v[8];

    for (int c = 0; c < 8; ++c) {
        __syncthreads();   // drains DMA: buf[c&1] ready
        if (c < 7) {
            const float4* gch = e1c + (c + 1) * 2048;
            #pragma unroll
            for (int j = 0; j < 8; ++j) {
                const int seg = wu * 512 + j * 64;
                gload_lds16(gch + seg + lane, &sE1[(c + 1) & 1][seg]);
            }
        }
        float acc = 0.f;
        const float4* buf = sE1[c & 1];
        #pragma unroll 1          // keep octants sequential: 64 SGPRs live max
        for (int oct = 0; oct < 4; ++oct) {
            float4 vcs[8], e2s[8];
            #pragma unroll
            for (int jq = 0; jq < 8; ++jq) {
                vcs[jq] = *(const float4*)&vc[(oct * 8 + jq) * 4];
                e2s[jq] = *(const float4*)&e2row[(oct * 8 + jq) * 4];
            }
            #pragma unroll
            for (int jq = 0; jq < 8; ++jq) {
                const int q = oct * 8 + jq;
                const float4 e1 = buf[q * 64 + (lane ^ q)];
                const float4 vv = vcs[jq];
                const float4 ee = e2s[jq];
                const float f1 = fmaf(e1.x, ee.x, 1.f);
                const float f2 = fmaf(e1.y, ee.y, 1.f);
                const float f3 = fmaf(e1.z, ee.z, 1.f);
                const float f4 = fmaf(e1.w, ee.w, 1.f);
                const float f12 = f1 * f2, f34 = f3 * f4;
                const float n12 = fmaf(vv.x, f2, vv.y * f1);
                const float n34 = fmaf(vv.z, f4, vv.w * f3);
                const float num = fmaf(n12, f34, n34 * f12);
                acc = fmaf(num, __builtin_amdgcn_rcpf(f12 * f34), acc);
            }
        }
        v[c] = -2.f * acc;   // score for s = c*64 + lane
    }

    // in-wave softmax over this wave's 512 scores
    float m = -1e30f;
    #pragma unroll
    for (int j = 0; j < 8; ++j) m = fmaxf(m, v[j]);
    #pragma unroll
    for (int off = 32; off; off >>= 1) m = fmaxf(m, __shfl_xor(m, off));
    float sum = 0.f;
    #pragma unroll
    for (int j = 0; j < 8; ++j) {
        v[j] = __builtin_amdgcn_exp2f((v[j] - m) * LOG2E);
        sum += v[j];
    }
    #pragma unroll
    for (int off = 32; off; off >>= 1) sum += __shfl_xor(sum, off);
    const float inv = __builtin_amdgcn_rcpf(sum);
    float* Prow = &P[(b * SEQ + t0 + w) * SEQ];
    #pragma unroll
    for (int j = 0; j < 8; ++j)
        Prow[j * 64 + lane] = v[j] * inv;
}

// ---------------- Kernel C: out = P @ x (proven R9 shape) ------------------
__global__ __launch_bounds__(256) void pax_kernel(
    const float* __restrict__ P, const float* __restrict__ x,
    float* __restrict__ out)
{
    __shared__ float sP[SEQ * 8];        // 16 KB: [s][t]
    __shared__ float sRed[4 * 8 * DDIM]; // 32 KB: [w][t][d]
    const int tid = threadIdx.x;
    const int b   = blockIdx.x >> 6;
    const int t0  = (blockIdx.x & 63) * 8;
    const int w    = tid >> 6;
    const int lane = tid & 63;

    #pragma unroll
    for (int j = 0; j < 4; ++j) {
        const int i = tid + j * 256;          // [0,1024): t = i>>7, c4 = i&127
        const int t = i >> 7, c4 = i & 127;
        const float4 p = *(const float4*)&P[(b * SEQ + t0 + t) * SEQ + c4 * 4];
        sP[(c4 * 4 + 0) * 8 + t] = p.x;
        sP[(c4 * 4 + 1) * 8 + t] = p.y;
        sP[(c4 * 4 + 2) * 8 + t] = p.z;
        sP[(c4 * 4 + 3) * 8 + t] = p.w;
    }
    __syncthreads();

    const float4* x4 = (const float4*)x;
    float4 acc[8];
    #pragma unroll
    for (int t = 0; t < 8; ++t) acc[t] = make_float4(0.f, 0.f, 0.f, 0.f);

    #pragma unroll 4
    for (int si = 0; si < 128; ++si) {
        const int s = w * 128 + si;
        const float4 xv  = x4[(b * SEQ + s) * 64 + lane];
        const float4 p03 = *(const float4*)&sP[s * 8];
        const float4 p47 = *(const float4*)&sP[s * 8 + 4];
        acc[0].x = fmaf(p03.x, xv.x, acc[0].x); acc[0].y = fmaf(p03.x, xv.y, acc[0].y);
        acc[0].z = fmaf(p03.x, xv.z, acc[0].z); acc[0].w = fmaf(p03.x, xv.w, acc[0].w);
        acc[1].x = fmaf(p03.y, xv.x, acc[1].x); acc[1].y = fmaf(p03.y, xv.y, acc[1].y);
        acc[1].z = fmaf(p03.y, xv.z, acc[1].z); acc[1].w = fmaf(p03.y, xv.w, acc[1].w);
        acc[2].x = fmaf(p03.z, xv.x, acc[2].x); acc[2].y = fmaf(p03.z, xv.y, acc[2].y);
        acc[2].z = fmaf(p03.z, xv.z, acc[2].z); acc[2].w = fmaf(p03.z, xv.w, acc[2].w);
        acc[3].x = fmaf(p03.w, xv.x, acc[3].x); acc[3].y = fmaf(p03.w, xv.y, acc[3].y);
        acc[3].z = fmaf(p03.w, xv.z, acc[3].z); acc[3].w = fmaf(p03.w, xv.w, acc[3].w);
        acc[4].x = fmaf(p47.x, xv.x, acc[4].x); acc[4].y = fmaf(p47.x, xv.y, acc[4].y);
        acc[4].z = fmaf(p47.x, xv.z, acc[4].z); acc[4].w = fmaf(p47.x, xv.w, acc[4].w);
        acc[5].x = fmaf(p47.y, xv.x, acc[5].x); acc[5].y = fmaf(p47.y, xv.y, acc[5].y);
        acc[5].z = fmaf(p47.y, xv.z, acc[5].z); acc[5].w = fmaf(p47.y, xv.w, acc[5].w);
        acc[6].x = fmaf(p47.z, xv.x, acc[6].x); acc[6].y = fmaf(p47.z, xv.y, acc[6].y);
        acc[6].z = fmaf(p47.z, xv.z, acc[6].z); acc[6].w = fmaf(p47.z, xv.w, acc[6].w);
        acc[7].x = fmaf(p47.w, xv.x, acc[7].x); acc[7].y = fmaf(p47.w, xv.y, acc[7].y);
        acc[7].z = fmaf(p47.w, xv.z, acc[7].z); acc[7].w = fmaf(p47.w, xv.w, acc[7].w);
    }
    __syncthreads();
    float4* sRed4 = (float4*)sRed;     // [4 w][8 t][64 lanes]
    #pragma unroll
    for (int t = 0; t < 8; ++t)
        sRed4[w * 512 + t * 64 + lane] = acc[t];
    __syncthreads();
    #pragma unroll
    for (int j = 0; j < 8; ++j) {
        const int i = tid + j * 256;   // [0,2048): t = i>>8, d = i&255
        const int t = i >> 8, d = i & 255;
        const float r = sRed[0*2048 + t*256 + d] + sRed[1*2048 + t*256 + d]
                      + sRed[2*2048 + t*256 + d] + sRed[3*2048 + t*256 + d];
        out[(b * SEQ + t0 + t) * DDIM + d] = r;
    }
}

extern "C" void kernel_launch(void* const* d_in, const int* in_sizes, int n_in,
                              void* d_out, int out_size, void* d_ws, size_t ws_size,
                              hipStream_t stream) {
    const float* x   = (const float*)d_in[0];   // (4,512,256)
    const float* y   = (const float*)d_in[1];   // (4,512,256)
    const float* W1  = (const float*)d_in[2];   // (128,256)
    const float* W2  = (const float*)d_in[3];   // (128,256)
    const float* vc  = (const float*)d_in[4];   // (1,128)
    float* outp = (float*)d_out;                // (4,512,256)

    float* ws = (float*)d_ws;
    float* e1 = ws;                             // 1 MB (swizzled)
    float* e2 = ws + NB * SEQ * HDIM;           // 1 MB
    float* P  = ws + 2 * NB * SEQ * HDIM;       // 4 MB

    hipLaunchKernelGGL(proj_kernel,  dim3(512), dim3(256), 0, stream,
                       x, y, W1, W2, e1, e2);
    hipLaunchKernelGGL(score_kernel, dim3(512), dim3(256), 0, stream,
                       e1, e2, vc, P);
    hipLaunchKernelGGL(pax_kernel,   dim3(256), dim3(256), 0, stream,
                       P, x, outp);
}